// Round 1
// baseline (674.752 us; speedup 1.0000x reference)
//
#include <hip/hip_runtime.h>
#include <hip/hip_bf16.h>
#include <math.h>

#define B 64
#define T 512
#define C 384
#define H 64

// ---------------------------------------------------------------------------
// Kernel A: fused q/k/v projection. One 64-thread block per (b,t) row.
// Stage x row (384 floats) in LDS; lane h computes dot(x_row, W*[:,h]) for
// all three weight matrices in one pass (reuses the broadcast LDS read).
// ---------------------------------------------------------------------------
__global__ __launch_bounds__(64) void proj_kernel(
    const float* __restrict__ x,
    const float* __restrict__ Wq,
    const float* __restrict__ Wk,
    const float* __restrict__ Wv,
    float* __restrict__ q,
    float* __restrict__ k,
    float* __restrict__ v) {
  const int row = blockIdx.x;          // b*T + t
  const int lane = threadIdx.x;        // 0..63 == head dim h

  __shared__ float xs[C];
  const float* xrow = x + (size_t)row * C;
#pragma unroll
  for (int i = 0; i < C / 64; ++i) {
    xs[lane + 64 * i] = xrow[lane + 64 * i];
  }
  __syncthreads();

  float aq = 0.f, ak = 0.f, av = 0.f;
#pragma unroll 8
  for (int c = 0; c < C; ++c) {
    const float xv = xs[c];                      // broadcast across lanes
    aq = fmaf(xv, Wq[c * H + lane], aq);          // coalesced across lanes
    ak = fmaf(xv, Wk[c * H + lane], ak);
    av = fmaf(xv, Wv[c * H + lane], av);
  }
  const size_t o = (size_t)row * H + lane;
  q[o] = aq;
  k[o] = ak;
  v[o] = av;
}

// ---------------------------------------------------------------------------
// Kernel B: causal attention for one query row per 64-lane wave.
// Pass 1: lane-strided over keys j<=t, score_j = dot(q_row, k_j)*scale -> LDS.
// Wave shuffle-reduce max; exp+sum; shuffle-reduce sum.
// Pass 2: lane == h, out[h] = (1/sum) * sum_j p_j * v[j][h] (coalesced v).
// ---------------------------------------------------------------------------
__global__ __launch_bounds__(64) void attn_kernel(
    const float* __restrict__ q,
    const float* __restrict__ k,
    const float* __restrict__ v,
    float* __restrict__ out) {
  const int row = blockIdx.x;          // b*T + t
  const int b = row / T;
  const int t = row % T;
  const int lane = threadIdx.x;

  __shared__ float sq[H];
  __shared__ float p[T];

  sq[lane] = q[(size_t)row * H + lane];
  __syncthreads();

  const float scale = 0.125f;          // 1/sqrt(64)

  // scores
  float maxv = -INFINITY;
  for (int j = lane; j <= t; j += 64) {
    const float* kj = k + ((size_t)b * T + j) * H;
    float s = 0.f;
#pragma unroll
    for (int c = 0; c < H; ++c) s = fmaf(sq[c], kj[c], s);
    s *= scale;
    p[j] = s;
    maxv = fmaxf(maxv, s);
  }
#pragma unroll
  for (int off = 32; off >= 1; off >>= 1)
    maxv = fmaxf(maxv, __shfl_xor(maxv, off));

  __syncthreads();

  float sum = 0.f;
  for (int j = lane; j <= t; j += 64) {
    const float e = __expf(p[j] - maxv);
    p[j] = e;
    sum += e;
  }
#pragma unroll
  for (int off = 32; off >= 1; off >>= 1)
    sum += __shfl_xor(sum, off);
  const float inv = 1.f / sum;

  __syncthreads();

  // weighted sum of v rows; lane == output head dim h
  float acc = 0.f;
  const float* vb = v + (size_t)b * T * H;
  for (int j = 0; j <= t; ++j) {
    acc = fmaf(p[j], vb[(size_t)j * H + lane], acc);
  }
  out[(size_t)row * H + lane] = acc * inv;
}

extern "C" void kernel_launch(void* const* d_in, const int* in_sizes, int n_in,
                              void* d_out, int out_size, void* d_ws, size_t ws_size,
                              hipStream_t stream) {
  const float* x  = (const float*)d_in[0];
  const float* Wq = (const float*)d_in[1];
  const float* Wk = (const float*)d_in[2];
  const float* Wv = (const float*)d_in[3];

  float* q = (float*)d_ws;
  float* k = q + (size_t)B * T * H;
  float* v = k + (size_t)B * T * H;
  float* out = (float*)d_out;

  proj_kernel<<<B * T, 64, 0, stream>>>(x, Wq, Wk, Wv, q, k, v);
  attn_kernel<<<B * T, 64, 0, stream>>>(q, k, v, out);
}

// Round 2
// 123.062 us; speedup vs baseline: 5.4830x; 5.4830x over previous
//
#include <hip/hip_runtime.h>
#include <math.h>

// Problem: B=64, T=512, C=384, H=64. fp32 in/out; bf16 MFMA internally.
#define NB 64
#define NT 512
#define NC 384
#define NH 64

typedef __attribute__((ext_vector_type(8))) short bf16x8;
typedef __attribute__((ext_vector_type(4))) float f32x4;

__device__ __forceinline__ unsigned short f2bf(float f) {
  unsigned int u = __float_as_uint(f);
  unsigned int r = (u + 0x7FFFu + ((u >> 16) & 1u)) >> 16;
  return (unsigned short)r;
}

// ---------------------------------------------------------------------------
// Kernel 0: W[3][384][64] fp32 -> Wt[3*64][384] bf16 (transposed, row-major)
// 73728 elements total; tiny.
// ---------------------------------------------------------------------------
__global__ __launch_bounds__(256) void wtrans_kernel(
    const float* __restrict__ Wq, const float* __restrict__ Wk,
    const float* __restrict__ Wv, unsigned short* __restrict__ Wt) {
  int id = blockIdx.x * 256 + threadIdx.x;
  if (id >= 3 * NC * NH) return;
  int m = id / (NC * NH);
  int r = id % (NC * NH);
  int c = r / NH;
  int h = r % NH;
  const float* W = (m == 0) ? Wq : ((m == 1) ? Wk : Wv);
  Wt[(m * NH + h) * NC + c] = f2bf(W[c * NH + h]);
}

// ---------------------------------------------------------------------------
// Kernel 1: fused QKV projection GEMM via MFMA.
// M=32768 rows of x, K=384, N=192 (q|k|v). Block = 256 thr = 4 waves,
// M-tile 64 (16 rows/wave). x tile staged bf16 in LDS (stride 392 = pad),
// Wt K-slices (192x32) staged per chunk (stride 40 = pad).
// ---------------------------------------------------------------------------
#define XS 392
#define WS 40
__global__ __launch_bounds__(256) void proj_kernel(
    const float* __restrict__ x, const unsigned short* __restrict__ Wt,
    unsigned short* __restrict__ qkv) {
  __shared__ unsigned short xs[64 * XS];   // 50176 B
  __shared__ unsigned short ws[192 * WS];  // 15360 B
  const int t = threadIdx.x;
  const int m0 = blockIdx.x * 64;
  const int w = t >> 6, l = t & 63, mi = l & 15, quad = l >> 4;

  // stage x tile: 64 rows x 384, fp32 -> bf16
  for (int i = 0; i < 24; ++i) {
    int u = t + i * 256;          // 6144 chunks of 4 floats
    int row = u / 96;
    int cp = (u % 96) * 4;
    const float* src = x + (size_t)(m0 + row) * NC + cp;
    float4 a = *(const float4*)src;
    ushort4 bb;
    bb.x = f2bf(a.x); bb.y = f2bf(a.y); bb.z = f2bf(a.z); bb.w = f2bf(a.w);
    *(ushort4*)&xs[row * XS + cp] = bb;
  }

  f32x4 acc[12];
  const f32x4 zero = {0.f, 0.f, 0.f, 0.f};
#pragma unroll
  for (int i = 0; i < 12; ++i) acc[i] = zero;

  for (int kc = 0; kc < 12; ++kc) {
    const int c0 = kc * 32;
    __syncthreads();  // protect ws from previous iter reads (+ xs ready, iter0)
#pragma unroll
    for (int i = 0; i < 3; ++i) {
      int u = t + i * 256;        // 768 units of 8 bf16
      int row = u >> 2;
      int seg = u & 3;
      *(uint4*)&ws[row * WS + seg * 8] =
          *(const uint4*)&Wt[row * NC + c0 + seg * 8];
    }
    __syncthreads();
    bf16x8 a = *(const bf16x8*)&xs[(w * 16 + mi) * XS + c0 + quad * 8];
#pragma unroll
    for (int nt = 0; nt < 12; ++nt) {
      bf16x8 b = *(const bf16x8*)&ws[(nt * 16 + mi) * WS + quad * 8];
      acc[nt] = __builtin_amdgcn_mfma_f32_16x16x32_bf16(a, b, acc[nt], 0, 0, 0);
    }
  }

  // epilogue: C/D layout col=lane&15, row=quad*4+r
#pragma unroll
  for (int nt = 0; nt < 12; ++nt) {
    int n = nt * 16 + mi;
    int mat = n >> 6;
    int h = n & 63;
    unsigned short* dst = qkv + (size_t)mat * (32768 * 64);
#pragma unroll
    for (int r = 0; r < 4; ++r) {
      int row = m0 + w * 16 + quad * 4 + r;
      dst[(size_t)row * NH + h] = f2bf(acc[nt][r]);
    }
  }
}

// ---------------------------------------------------------------------------
// Kernel 2: causal flash attention, bf16 MFMA.
// Block = 256 thr (4 waves), one (batch b, q-tile of 64 rows). Wave w owns
// q-rows w*16..+15. Iterate k-tiles 0..qt with online softmax.
// LDS tiles padded to stride 72 (144 B, 16B-aligned, conflict-light).
// ---------------------------------------------------------------------------
#define AS 72
__global__ __launch_bounds__(256) void attn_kernel(
    const unsigned short* __restrict__ q, const unsigned short* __restrict__ k,
    const unsigned short* __restrict__ v, float* __restrict__ out) {
  __shared__ unsigned short qs[64 * AS];
  __shared__ unsigned short ks[64 * AS];
  __shared__ unsigned short vts[64 * AS];  // V transposed: [h][j]
  __shared__ unsigned short ps[64 * AS];   // P round-trip (per-wave 16-row bands)

  const int t = threadIdx.x;
  const int bx = blockIdx.x;
  const int qt = 7 - (bx >> 6);   // heavy q-tiles dispatched first
  const int b = bx & 63;
  const int w = t >> 6, l = t & 63, mi = l & 15, quad = l >> 4;

  const size_t qbase = ((size_t)b * NT + qt * 64) * NH;
#pragma unroll
  for (int i = 0; i < 2; ++i) {
    int u = t + i * 256;
    int row = u >> 3, seg = u & 7;
    *(uint4*)&qs[row * AS + seg * 8] = *(const uint4*)&q[qbase + row * 64 + seg * 8];
  }

  f32x4 accO[4];
  const f32x4 zero = {0.f, 0.f, 0.f, 0.f};
#pragma unroll
  for (int i = 0; i < 4; ++i) accO[i] = zero;
  float mrow[4], lrow[4];
#pragma unroll
  for (int r = 0; r < 4; ++r) { mrow[r] = -INFINITY; lrow[r] = 0.f; }

  for (int kt = 0; kt <= qt; ++kt) {
    const size_t kbase = ((size_t)b * NT + kt * 64) * NH;
    __syncthreads();  // prev tile reads done before restaging
#pragma unroll
    for (int i = 0; i < 2; ++i) {
      int u = t + i * 256;
      int row = u >> 3, seg = u & 7;
      *(uint4*)&ks[row * AS + seg * 8] = *(const uint4*)&k[kbase + row * 64 + seg * 8];
    }
    {  // V transposed staging
      int row = t >> 2;
      int h0 = (t & 3) * 16;
      unsigned short tmp[16];
      *(uint4*)&tmp[0] = *(const uint4*)&v[kbase + row * 64 + h0];
      *(uint4*)&tmp[8] = *(const uint4*)&v[kbase + row * 64 + h0 + 8];
#pragma unroll
      for (int i = 0; i < 16; ++i) vts[(h0 + i) * AS + row] = tmp[i];
    }
    __syncthreads();

    // S = Q K^T  (A: qs rows, B: ks rows; D col=key, row=qrow)
    f32x4 s[4];
    bf16x8 a0 = *(const bf16x8*)&qs[(w * 16 + mi) * AS + quad * 8];
    bf16x8 a1 = *(const bf16x8*)&qs[(w * 16 + mi) * AS + 32 + quad * 8];
#pragma unroll
    for (int nt = 0; nt < 4; ++nt) {
      bf16x8 b0 = *(const bf16x8*)&ks[(nt * 16 + mi) * AS + quad * 8];
      bf16x8 b1 = *(const bf16x8*)&ks[(nt * 16 + mi) * AS + 32 + quad * 8];
      f32x4 z = zero;
      z = __builtin_amdgcn_mfma_f32_16x16x32_bf16(a0, b0, z, 0, 0, 0);
      z = __builtin_amdgcn_mfma_f32_16x16x32_bf16(a1, b1, z, 0, 0, 0);
      s[nt] = z;
    }
#pragma unroll
    for (int nt = 0; nt < 4; ++nt)
#pragma unroll
      for (int r = 0; r < 4; ++r) s[nt][r] *= 0.125f;

    if (kt == qt) {  // causal mask on diagonal tile
#pragma unroll
      for (int nt = 0; nt < 4; ++nt) {
        int key = nt * 16 + mi;
#pragma unroll
        for (int r = 0; r < 4; ++r) {
          int qrow = w * 16 + quad * 4 + r;
          if (key > qrow) s[nt][r] = -INFINITY;
        }
      }
    }

    // online softmax: row max over 64 keys (4 nt x 16 lanes of quad)
    float alpha[4];
#pragma unroll
    for (int r = 0; r < 4; ++r) {
      float v0 = fmaxf(fmaxf(s[0][r], s[1][r]), fmaxf(s[2][r], s[3][r]));
      v0 = fmaxf(v0, __shfl_xor(v0, 1));
      v0 = fmaxf(v0, __shfl_xor(v0, 2));
      v0 = fmaxf(v0, __shfl_xor(v0, 4));
      v0 = fmaxf(v0, __shfl_xor(v0, 8));
      float mn = fmaxf(mrow[r], v0);
      alpha[r] = __expf(mrow[r] - mn);
      mrow[r] = mn;
    }
    float rs[4] = {0.f, 0.f, 0.f, 0.f};
#pragma unroll
    for (int nt = 0; nt < 4; ++nt) {
#pragma unroll
      for (int r = 0; r < 4; ++r) {
        float p = __expf(s[nt][r] - mrow[r]);
        rs[r] += p;
        ps[(w * 16 + quad * 4 + r) * AS + nt * 16 + mi] = f2bf(p);
      }
    }
#pragma unroll
    for (int r = 0; r < 4; ++r) {
      float v0 = rs[r];
      v0 += __shfl_xor(v0, 1);
      v0 += __shfl_xor(v0, 2);
      v0 += __shfl_xor(v0, 4);
      v0 += __shfl_xor(v0, 8);
      lrow[r] = lrow[r] * alpha[r] + v0;
    }
#pragma unroll
    for (int nt = 0; nt < 4; ++nt)
#pragma unroll
      for (int r = 0; r < 4; ++r) accO[nt][r] *= alpha[r];

    __syncthreads();  // guarantee ps writes visible (also keeps waves in step)

    // O += P V   (A: ps rows m=lane&15 of this wave's band; B: vts[h][j])
    bf16x8 pa0 = *(const bf16x8*)&ps[(w * 16 + mi) * AS + quad * 8];
    bf16x8 pa1 = *(const bf16x8*)&ps[(w * 16 + mi) * AS + 32 + quad * 8];
#pragma unroll
    for (int nt = 0; nt < 4; ++nt) {
      bf16x8 vb0 = *(const bf16x8*)&vts[(nt * 16 + mi) * AS + quad * 8];
      bf16x8 vb1 = *(const bf16x8*)&vts[(nt * 16 + mi) * AS + 32 + quad * 8];
      accO[nt] = __builtin_amdgcn_mfma_f32_16x16x32_bf16(pa0, vb0, accO[nt], 0, 0, 0);
      accO[nt] = __builtin_amdgcn_mfma_f32_16x16x32_bf16(pa1, vb1, accO[nt], 0, 0, 0);
    }
  }

  // epilogue: out fp32, row-major [b][t][h]
  const size_t obase = ((size_t)b * NT + qt * 64) * NH;
#pragma unroll
  for (int nt = 0; nt < 4; ++nt) {
#pragma unroll
    for (int r = 0; r < 4; ++r) {
      out[obase + (size_t)(w * 16 + quad * 4 + r) * NH + nt * 16 + mi] =
          accO[nt][r] / lrow[r];
    }
  }
}

extern "C" void kernel_launch(void* const* d_in, const int* in_sizes, int n_in,
                              void* d_out, int out_size, void* d_ws, size_t ws_size,
                              hipStream_t stream) {
  const float* x  = (const float*)d_in[0];
  const float* Wq = (const float*)d_in[1];
  const float* Wk = (const float*)d_in[2];
  const float* Wv = (const float*)d_in[3];

  unsigned short* Wt = (unsigned short*)d_ws;          // 192*384 bf16
  unsigned short* qb = Wt + 192 * 384;                 // 32768*64 bf16 each
  unsigned short* kb = qb + 32768 * 64;
  unsigned short* vb = kb + 32768 * 64;
  float* out = (float*)d_out;

  wtrans_kernel<<<288, 256, 0, stream>>>(Wq, Wk, Wv, Wt);
  proj_kernel<<<512, 256, 0, stream>>>(x, Wt, qb);
  attn_kernel<<<512, 256, 0, stream>>>(qb, kb, vb, out);
}